// Round 12
// baseline (280.757 us; speedup 1.0000x reference)
//
#include <hip/hip_runtime.h>
#pragma clang fp contract(off)

// FROZEN NUMERICS (verified bit-exact vs harness np ref, r9/r10 absmax=0.0):
//   f32; flat row-major sequential 5x5 reflect taps;
//   s += a; q = fmaf(a,a,q);
//   mean = s*C25; msq = q*C25;           (reciprocal-multiply, arcp flavor)
//   var  = fmaf(-mean, mean, msq);       (fused final subtraction)
//   norm = (var-mn)/(mx-mn); lat = 1/(norm + f32(1/48));  (exact f32 fdiv)
//   mask = (t>=lat) & (t<lat+16) & (u<x)
// Do NOT alter any of these operations or their order.

#define IMG_H 512
#define IMG_W 512
#define IMG_B 8
#define NPIX  (IMG_B * IMG_H * IMG_W)   // 2,097,152
#define T_WIN 64
#define F_WIN 16
#define NV4   (NPIX * (T_WIN / 4))      // 33,554,432
#define INV48_F ((float)(1.0 / 48.0))
#define C25     ((float)(1.0 / 25.0))

#define KA_BLOCKS 2048
#define KC_BLOCKS 2048
#define K3_BLOCKS 4096

// Native clang vector type: accepted by __builtin_nontemporal_* (HIP's
// float4 class type is not). Same 16-byte layout as 4 packed floats.
typedef float nfloat4 __attribute__((ext_vector_type(4)));
typedef float nfloat2 __attribute__((ext_vector_type(2)));

__device__ float   g_var[NPIX];
__device__ nfloat2 g_lx[NPIX];           // {lat, x} packed per pixel
__device__ float   g_part[2][KA_BLOCKS]; // min, max partials
__device__ float   g_mm[2];

// 5x5 reflect-padded variance at pixel p (frozen numerics).
__device__ __forceinline__ float var_at(const float* __restrict__ x, int p)
{
    const int b   = p >> 18;
    const int rem = p & 0x3FFFF;
    const int h   = rem >> 9;
    const int w   = rem & 511;
    const float* img = x + (b << 18);
    float s = 0.0f, q = 0.0f;
    #pragma unroll
    for (int dy = -2; dy <= 2; ++dy) {
        int hh = h + dy;
        hh = (hh < 0) ? -hh : ((hh >= IMG_H) ? (2 * IMG_H - 2 - hh) : hh);
        const float* row = img + hh * IMG_W;
        #pragma unroll
        for (int dx = -2; dx <= 2; ++dx) {
            int ww = w + dx;
            ww = (ww < 0) ? -ww : ((ww >= IMG_W) ? (2 * IMG_W - 2 - ww) : ww);
            const float a = row[ww];
            s = s + a;
            q = fmaf(a, a, q);
        }
    }
    const float mean = s * C25;
    const float msq  = q * C25;
    return fmaf(-mean, mean, msq);
}

// kA: variance map + per-block min/max partials (2048 blocks, 4 iters).
__global__ __launch_bounds__(256) void kA(const float* __restrict__ x)
{
    const int tid = threadIdx.x;
    float mn = 3e38f, mx = -3e38f;
    for (int p = blockIdx.x * 256 + tid; p < NPIX; p += KA_BLOCKS * 256) {
        const float v = var_at(x, p);
        g_var[p] = v;
        mn = fminf(mn, v);
        mx = fmaxf(mx, v);
    }
    __shared__ float smn[256], smx[256];
    smn[tid] = mn;
    smx[tid] = mx;
    __syncthreads();
    #pragma unroll
    for (int s = 128; s > 0; s >>= 1) {
        if (tid < s) {
            smn[tid] = fminf(smn[tid], smn[tid + s]);
            smx[tid] = fmaxf(smx[tid], smx[tid + s]);
        }
        __syncthreads();
    }
    if (tid == 0) {
        g_part[0][blockIdx.x] = smn[0];
        g_part[1][blockIdx.x] = smx[0];
    }
}

// kB: fold KA_BLOCKS partials into g_mm = {min, max}.
__global__ __launch_bounds__(256) void kB()
{
    const int tid = threadIdx.x;
    float mn = 3e38f, mx = -3e38f;
    for (int i = tid; i < KA_BLOCKS; i += 256) {
        mn = fminf(mn, g_part[0][i]);
        mx = fmaxf(mx, g_part[1][i]);
    }
    __shared__ float smn[256], smx[256];
    smn[tid] = mn;
    smx[tid] = mx;
    __syncthreads();
    #pragma unroll
    for (int s = 128; s > 0; s >>= 1) {
        if (tid < s) {
            smn[tid] = fminf(smn[tid], smn[tid + s]);
            smx[tid] = fmaxf(smx[tid], smx[tid + s]);
        }
        __syncthreads();
    }
    if (tid == 0) {
        g_mm[0] = smn[0];
        g_mm[1] = smx[0];
    }
}

// kC: pack per-pixel {lat, x} (frozen lat chain, op-for-op).
__global__ __launch_bounds__(256) void kC(const float* __restrict__ x)
{
    const float mn = g_mm[0];
    const float mx = g_mm[1];
    for (int p = blockIdx.x * 256 + threadIdx.x; p < NPIX; p += KC_BLOCKS * 256) {
        const float n = (g_var[p] - mn) / (mx - mn);
        const float d = n + INV48_F;
        nfloat2 lx;
        lx.x = 1.0f / d;
        lx.y = x[p];
        g_lx[p] = lx;
    }
}

// k3: pure streaming kernel, LDS-free, grid-stride (4096 blocks, 32 iters).
// vec&15 is iteration-invariant (stride is a multiple of 16), so each
// thread's four t values are compile-time-fixed per thread. Wave covers
// 4 KB contiguous u/out per iteration; nt hints bypass L2 for the stream,
// keeping g_lx (16 MB) L2-resident.
__global__ __launch_bounds__(256) void k3(const nfloat4* __restrict__ u4,
                                          nfloat4* __restrict__ out4)
{
    const int vec0 = blockIdx.x * 256 + threadIdx.x;
    const int c    = vec0 & 15;
    const float tb0 = (float)(c * 4);
    const float tb1 = tb0 + 1.0f;
    const float tb2 = tb0 + 2.0f;
    const float tb3 = tb0 + 3.0f;

    int vec = vec0;
    int pix = vec0 >> 4;
    #pragma unroll 4
    for (int it = 0; it < NV4 / (K3_BLOCKS * 256); ++it) {
        const nfloat2 lx  = g_lx[pix];
        const float   lat = lx.x;
        const float   xv  = lx.y;
        const float   hi  = lat + 16.0f;
        const nfloat4 uu  = __builtin_nontemporal_load(u4 + vec);
        nfloat4 o;
        o.x = (tb0 >= lat && tb0 < hi && uu.x < xv) ? 1.0f : 0.0f;
        o.y = (tb1 >= lat && tb1 < hi && uu.y < xv) ? 1.0f : 0.0f;
        o.z = (tb2 >= lat && tb2 < hi && uu.z < xv) ? 1.0f : 0.0f;
        o.w = (tb3 >= lat && tb3 < hi && uu.w < xv) ? 1.0f : 0.0f;
        __builtin_nontemporal_store(o, out4 + vec);
        vec += K3_BLOCKS * 256;
        pix += (K3_BLOCKS * 256) / 16;
    }
}

extern "C" void kernel_launch(void* const* d_in, const int* in_sizes, int n_in,
                              void* d_out, int out_size, void* d_ws, size_t ws_size,
                              hipStream_t stream)
{
    const float* x = nullptr;
    const float* u = nullptr;
    for (int i = 0; i < n_in; ++i) {
        if (in_sizes[i] == NPIX)              x = (const float*)d_in[i];
        else if (in_sizes[i] == NPIX * T_WIN) u = (const float*)d_in[i];
    }
    if (!x) x = (const float*)d_in[0];
    if (!u) u = (const float*)d_in[1];
    float* out = (float*)d_out;

    kA<<<KA_BLOCKS, 256, 0, stream>>>(x);
    kB<<<1, 256, 0, stream>>>();
    kC<<<KC_BLOCKS, 256, 0, stream>>>(x);
    k3<<<K3_BLOCKS, 256, 0, stream>>>((const nfloat4*)u, (nfloat4*)out);
}

// Round 13
// 215.556 us; speedup vs baseline: 1.3025x; 1.3025x over previous
//
#include <hip/hip_runtime.h>
#pragma clang fp contract(off)

// FROZEN NUMERICS (verified bit-exact vs harness np ref, r9/r10/r12 absmax=0.0):
//   f32; flat row-major sequential 5x5 reflect taps;
//   s += a; q = fmaf(a,a,q);
//   mean = s*C25; msq = q*C25;           (reciprocal-multiply, arcp flavor)
//   var  = fmaf(-mean, mean, msq);       (fused final subtraction)
//   norm = (var-mn)/(mx-mn); lat = 1/(norm + f32(1/48));  (exact f32 fdiv)
//   mask = (t>=lat) & (t<lat+16) & (u<x)
// Do NOT alter any of these operations or their order.
//
// Perf journal: r10 (LDS-phase k3, plain st) 224µs PASS; r12 (nt + grid-stride)
// 281µs REGRESSION -> nt hints dropped, r10 geometry restored.

#define IMG_H 512
#define IMG_W 512
#define IMG_B 8
#define NPIX  (IMG_B * IMG_H * IMG_W)   // 2,097,152
#define T_WIN 64
#define F_WIN 16
#define NV4   (NPIX * (T_WIN / 4))      // 33,554,432
#define INV48_F ((float)(1.0 / 48.0))
#define C25     ((float)(1.0 / 25.0))

#define KA_BLOCKS 2048
#define KC_BLOCKS 2048

__device__ float  g_var[NPIX];
__device__ float2 g_lx[NPIX];           // {lat, x} packed per pixel
__device__ float  g_part[2][KA_BLOCKS]; // min, max partials
__device__ float  g_mm[2];

// 5x5 reflect-padded variance at pixel p (frozen numerics).
__device__ __forceinline__ float var_at(const float* __restrict__ x, int p)
{
    const int b   = p >> 18;
    const int rem = p & 0x3FFFF;
    const int h   = rem >> 9;
    const int w   = rem & 511;
    const float* img = x + (b << 18);
    float s = 0.0f, q = 0.0f;
    #pragma unroll
    for (int dy = -2; dy <= 2; ++dy) {
        int hh = h + dy;
        hh = (hh < 0) ? -hh : ((hh >= IMG_H) ? (2 * IMG_H - 2 - hh) : hh);
        const float* row = img + hh * IMG_W;
        #pragma unroll
        for (int dx = -2; dx <= 2; ++dx) {
            int ww = w + dx;
            ww = (ww < 0) ? -ww : ((ww >= IMG_W) ? (2 * IMG_W - 2 - ww) : ww);
            const float a = row[ww];
            s = s + a;
            q = fmaf(a, a, q);
        }
    }
    const float mean = s * C25;
    const float msq  = q * C25;
    return fmaf(-mean, mean, msq);
}

// kA: variance map + per-block min/max partials (2048 blocks, 4 iters/thread).
__global__ __launch_bounds__(256) void kA(const float* __restrict__ x)
{
    const int tid = threadIdx.x;
    float mn = 3e38f, mx = -3e38f;
    for (int p = blockIdx.x * 256 + tid; p < NPIX; p += KA_BLOCKS * 256) {
        const float v = var_at(x, p);
        g_var[p] = v;
        mn = fminf(mn, v);
        mx = fmaxf(mx, v);
    }
    __shared__ float smn[256], smx[256];
    smn[tid] = mn;
    smx[tid] = mx;
    __syncthreads();
    #pragma unroll
    for (int s = 128; s > 0; s >>= 1) {
        if (tid < s) {
            smn[tid] = fminf(smn[tid], smn[tid + s]);
            smx[tid] = fmaxf(smx[tid], smx[tid + s]);
        }
        __syncthreads();
    }
    if (tid == 0) {
        g_part[0][blockIdx.x] = smn[0];
        g_part[1][blockIdx.x] = smx[0];
    }
}

// kB: fold KA_BLOCKS partials into g_mm = {min, max}.
__global__ __launch_bounds__(256) void kB()
{
    const int tid = threadIdx.x;
    float mn = 3e38f, mx = -3e38f;
    for (int i = tid; i < KA_BLOCKS; i += 256) {
        mn = fminf(mn, g_part[0][i]);
        mx = fmaxf(mx, g_part[1][i]);
    }
    __shared__ float smn[256], smx[256];
    smn[tid] = mn;
    smx[tid] = mx;
    __syncthreads();
    #pragma unroll
    for (int s = 128; s > 0; s >>= 1) {
        if (tid < s) {
            smn[tid] = fminf(smn[tid], smn[tid + s]);
            smx[tid] = fmaxf(smx[tid], smx[tid + s]);
        }
        __syncthreads();
    }
    if (tid == 0) {
        g_mm[0] = smn[0];
        g_mm[1] = smx[0];
    }
}

// kC: pack per-pixel {lat, x} (frozen lat chain, op-for-op).
__global__ __launch_bounds__(256) void kC(const float* __restrict__ x)
{
    const float mn = g_mm[0];
    const float mx = g_mm[1];
    for (int p = blockIdx.x * 256 + threadIdx.x; p < NPIX; p += KC_BLOCKS * 256) {
        const float n = (g_var[p] - mn) / (mx - mn);
        const float d = n + INV48_F;
        float2 lx;
        lx.x = 1.0f / d;
        lx.y = x[p];
        g_lx[p] = lx;
    }
}

// k3: r10 geometry (64 pixels / 1024 float4 per block), no LDS, no sync:
// per-pixel {lat,x} comes from g_lx (8B, 16-lane broadcast, L2-resident).
// Each iteration the wave touches 4 KB contiguous u and out. Plain loads
// and stores (nt hints measured -25% in r12).
__global__ __launch_bounds__(256) void k3(const float2* __restrict__ lx2,
                                          const float4* __restrict__ u4,
                                          float4* __restrict__ out4)
{
    const int tid     = threadIdx.x;
    const int vecbase = blockIdx.x * 1024;
    const int pixbase = blockIdx.x * 64;
    const float t0 = (float)((tid & 15) * 4);
    const float t1 = t0 + 1.0f;
    const float t2 = t0 + 2.0f;
    const float t3 = t0 + 3.0f;

    #pragma unroll
    for (int j = 0; j < 4; ++j) {
        const int vec = vecbase + j * 256 + tid;
        const float2 lx  = lx2[pixbase + j * 16 + (tid >> 4)];
        const float  lat = lx.x;
        const float  xv  = lx.y;
        const float  hi  = lat + 16.0f;
        const float4 uu  = u4[vec];
        float4 o;
        o.x = (t0 >= lat && t0 < hi && uu.x < xv) ? 1.0f : 0.0f;
        o.y = (t1 >= lat && t1 < hi && uu.y < xv) ? 1.0f : 0.0f;
        o.z = (t2 >= lat && t2 < hi && uu.z < xv) ? 1.0f : 0.0f;
        o.w = (t3 >= lat && t3 < hi && uu.w < xv) ? 1.0f : 0.0f;
        out4[vec] = o;
    }
}

extern "C" void kernel_launch(void* const* d_in, const int* in_sizes, int n_in,
                              void* d_out, int out_size, void* d_ws, size_t ws_size,
                              hipStream_t stream)
{
    const float* x = nullptr;
    const float* u = nullptr;
    for (int i = 0; i < n_in; ++i) {
        if (in_sizes[i] == NPIX)              x = (const float*)d_in[i];
        else if (in_sizes[i] == NPIX * T_WIN) u = (const float*)d_in[i];
    }
    if (!x) x = (const float*)d_in[0];
    if (!u) u = (const float*)d_in[1];
    float* out = (float*)d_out;

    kA<<<KA_BLOCKS, 256, 0, stream>>>(x);
    kB<<<1, 256, 0, stream>>>();
    kC<<<KC_BLOCKS, 256, 0, stream>>>(x);

    // One float2 pointer per pixel; g_lx is a __device__ global, get its
    // address via the symbol directly (valid in device-code address space).
    float2* lxp = nullptr;
    hipGetSymbolAddress((void**)&lxp, HIP_SYMBOL(g_lx));
    k3<<<NPIX / 64, 256, 0, stream>>>(lxp, (const float4*)u, (float4*)out);
}

// Round 14
// 209.495 us; speedup vs baseline: 1.3402x; 1.0289x over previous
//
#include <hip/hip_runtime.h>
#pragma clang fp contract(off)

// FROZEN NUMERICS (verified bit-exact vs harness np ref, r9/r10/r12/r13 absmax=0.0):
//   f32; flat row-major sequential 5x5 reflect taps;
//   s += a; q = fmaf(a,a,q);
//   mean = s*C25; msq = q*C25;           (reciprocal-multiply, arcp flavor)
//   var  = fmaf(-mean, mean, msq);       (fused final subtraction)
//   norm = (var-mn)/(mx-mn); lat = 1/(norm + f32(1/48));  (exact f32 fdiv)
//   mask = (t>=lat) & (t<lat+16) & (u<x)
// Do NOT alter any of these operations or their order.
//
// Perf journal: r10 224.4 (LDS-phase k3) -> r12 280.8 REGRESSION (nt hints)
// -> r13 215.6 (g_lx table k3, plain st) -> r14: drop kC, inline lat in k3
// (2 broadcast loads + 2 fdiv per pixel-iter; VALU idle in streaming kernel).

#define IMG_H 512
#define IMG_W 512
#define IMG_B 8
#define NPIX  (IMG_B * IMG_H * IMG_W)   // 2,097,152
#define T_WIN 64
#define F_WIN 16
#define INV48_F ((float)(1.0 / 48.0))
#define C25     ((float)(1.0 / 25.0))

#define KA_BLOCKS 2048

__device__ float g_var[NPIX];
__device__ float g_part[2][KA_BLOCKS]; // min, max partials
__device__ float g_mm[2];

// 5x5 reflect-padded variance at pixel p (frozen numerics).
__device__ __forceinline__ float var_at(const float* __restrict__ x, int p)
{
    const int b   = p >> 18;
    const int rem = p & 0x3FFFF;
    const int h   = rem >> 9;
    const int w   = rem & 511;
    const float* img = x + (b << 18);
    float s = 0.0f, q = 0.0f;
    #pragma unroll
    for (int dy = -2; dy <= 2; ++dy) {
        int hh = h + dy;
        hh = (hh < 0) ? -hh : ((hh >= IMG_H) ? (2 * IMG_H - 2 - hh) : hh);
        const float* row = img + hh * IMG_W;
        #pragma unroll
        for (int dx = -2; dx <= 2; ++dx) {
            int ww = w + dx;
            ww = (ww < 0) ? -ww : ((ww >= IMG_W) ? (2 * IMG_W - 2 - ww) : ww);
            const float a = row[ww];
            s = s + a;
            q = fmaf(a, a, q);
        }
    }
    const float mean = s * C25;
    const float msq  = q * C25;
    return fmaf(-mean, mean, msq);
}

// kA: variance map + per-block min/max partials (2048 blocks, 4 iters/thread).
__global__ __launch_bounds__(256) void kA(const float* __restrict__ x)
{
    const int tid = threadIdx.x;
    float mn = 3e38f, mx = -3e38f;
    for (int p = blockIdx.x * 256 + tid; p < NPIX; p += KA_BLOCKS * 256) {
        const float v = var_at(x, p);
        g_var[p] = v;
        mn = fminf(mn, v);
        mx = fmaxf(mx, v);
    }
    __shared__ float smn[256], smx[256];
    smn[tid] = mn;
    smx[tid] = mx;
    __syncthreads();
    #pragma unroll
    for (int s = 128; s > 0; s >>= 1) {
        if (tid < s) {
            smn[tid] = fminf(smn[tid], smn[tid + s]);
            smx[tid] = fmaxf(smx[tid], smx[tid + s]);
        }
        __syncthreads();
    }
    if (tid == 0) {
        g_part[0][blockIdx.x] = smn[0];
        g_part[1][blockIdx.x] = smx[0];
    }
}

// kB: fold KA_BLOCKS partials into g_mm = {min, max}.
__global__ __launch_bounds__(256) void kB()
{
    const int tid = threadIdx.x;
    float mn = 3e38f, mx = -3e38f;
    for (int i = tid; i < KA_BLOCKS; i += 256) {
        mn = fminf(mn, g_part[0][i]);
        mx = fmaxf(mx, g_part[1][i]);
    }
    __shared__ float smn[256], smx[256];
    smn[tid] = mn;
    smx[tid] = mx;
    __syncthreads();
    #pragma unroll
    for (int s = 128; s > 0; s >>= 1) {
        if (tid < s) {
            smn[tid] = fminf(smn[tid], smn[tid + s]);
            smx[tid] = fmaxf(smx[tid], smx[tid + s]);
        }
        __syncthreads();
    }
    if (tid == 0) {
        g_mm[0] = smn[0];
        g_mm[1] = smx[0];
    }
}

// k3: streaming kernel, r13 geometry (64 pixels / 1024 float4 per block),
// no LDS, no sync. lat computed INLINE from g_var/x/g_mm (frozen op chain;
// 2 broadcast 4B loads + 2 exact fdivs per pixel-iter — VALU is idle in a
// memory-bound stream, and the independent u4 load issues ahead).
__global__ __launch_bounds__(256) void k3(const float* __restrict__ var,
                                          const float* __restrict__ x,
                                          const float4* __restrict__ u4,
                                          float4* __restrict__ out4)
{
    const int tid     = threadIdx.x;
    const int vecbase = blockIdx.x * 1024;
    const int pixbase = blockIdx.x * 64;
    const float t0 = (float)((tid & 15) * 4);
    const float t1 = t0 + 1.0f;
    const float t2 = t0 + 2.0f;
    const float t3 = t0 + 3.0f;
    const float mn = g_mm[0];
    const float mx = g_mm[1];

    #pragma unroll
    for (int j = 0; j < 4; ++j) {
        const int vec = vecbase + j * 256 + tid;
        const int pix = pixbase + j * 16 + (tid >> 4);
        const float4 uu = u4[vec];                 // independent, issues early
        const float n   = (var[pix] - mn) / (mx - mn);   // frozen lat chain
        const float d   = n + INV48_F;
        const float lat = 1.0f / d;
        const float hi  = lat + 16.0f;
        const float xv  = x[pix];
        float4 o;
        o.x = (t0 >= lat && t0 < hi && uu.x < xv) ? 1.0f : 0.0f;
        o.y = (t1 >= lat && t1 < hi && uu.y < xv) ? 1.0f : 0.0f;
        o.z = (t2 >= lat && t2 < hi && uu.z < xv) ? 1.0f : 0.0f;
        o.w = (t3 >= lat && t3 < hi && uu.w < xv) ? 1.0f : 0.0f;
        out4[vec] = o;
    }
}

extern "C" void kernel_launch(void* const* d_in, const int* in_sizes, int n_in,
                              void* d_out, int out_size, void* d_ws, size_t ws_size,
                              hipStream_t stream)
{
    const float* x = nullptr;
    const float* u = nullptr;
    for (int i = 0; i < n_in; ++i) {
        if (in_sizes[i] == NPIX)              x = (const float*)d_in[i];
        else if (in_sizes[i] == NPIX * T_WIN) u = (const float*)d_in[i];
    }
    if (!x) x = (const float*)d_in[0];
    if (!u) u = (const float*)d_in[1];
    float* out = (float*)d_out;

    kA<<<KA_BLOCKS, 256, 0, stream>>>(x);
    kB<<<1, 256, 0, stream>>>();

    float* varp = nullptr;
    hipGetSymbolAddress((void**)&varp, HIP_SYMBOL(g_var));
    k3<<<NPIX / 64, 256, 0, stream>>>(varp, x, (const float4*)u, (float4*)out);
}

// Round 15
// 174.260 us; speedup vs baseline: 1.6111x; 1.2022x over previous
//
#include <hip/hip_runtime.h>
#pragma clang fp contract(off)

// FROZEN NUMERICS (verified bit-exact vs harness np ref, r9-r14 absmax=0.0):
//   f32; flat row-major sequential 5x5 reflect taps;
//   s += a; q = fmaf(a,a,q);
//   mean = s*C25; msq = q*C25;           (reciprocal-multiply, arcp flavor)
//   var  = fmaf(-mean, mean, msq);       (fused final subtraction)
//   norm = (var-mn)/(mx-mn); lat = 1/(norm + f32(1/48));  (exact f32 fdiv)
//   mask = (t>=lat) & (t<lat+16) & (u<x)
// Do NOT alter any of these operations or their order.
//
// Perf journal: r10 224.4 -> r12 281 REGRESSION (nt hints) -> r13 215.6
// (g_lx table) -> r14 209.5 (inline lat, no kC) -> r15: SKIP u loads where
// the firing window misses the quad (out=0 regardless of u): exec-mask
// predication cuts u fetch ~537 -> ~350 MB at cache-line granularity.

#define IMG_H 512
#define IMG_W 512
#define IMG_B 8
#define NPIX  (IMG_B * IMG_H * IMG_W)   // 2,097,152
#define T_WIN 64
#define F_WIN 16
#define INV48_F ((float)(1.0 / 48.0))
#define C25     ((float)(1.0 / 25.0))

#define KA_BLOCKS 2048

__device__ float g_var[NPIX];
__device__ float g_part[2][KA_BLOCKS]; // min, max partials
__device__ float g_mm[2];

// 5x5 reflect-padded variance at pixel p (frozen numerics).
__device__ __forceinline__ float var_at(const float* __restrict__ x, int p)
{
    const int b   = p >> 18;
    const int rem = p & 0x3FFFF;
    const int h   = rem >> 9;
    const int w   = rem & 511;
    const float* img = x + (b << 18);
    float s = 0.0f, q = 0.0f;
    #pragma unroll
    for (int dy = -2; dy <= 2; ++dy) {
        int hh = h + dy;
        hh = (hh < 0) ? -hh : ((hh >= IMG_H) ? (2 * IMG_H - 2 - hh) : hh);
        const float* row = img + hh * IMG_W;
        #pragma unroll
        for (int dx = -2; dx <= 2; ++dx) {
            int ww = w + dx;
            ww = (ww < 0) ? -ww : ((ww >= IMG_W) ? (2 * IMG_W - 2 - ww) : ww);
            const float a = row[ww];
            s = s + a;
            q = fmaf(a, a, q);
        }
    }
    const float mean = s * C25;
    const float msq  = q * C25;
    return fmaf(-mean, mean, msq);
}

// kA: variance map + per-block min/max partials (2048 blocks, 4 iters/thread).
__global__ __launch_bounds__(256) void kA(const float* __restrict__ x)
{
    const int tid = threadIdx.x;
    float mn = 3e38f, mx = -3e38f;
    for (int p = blockIdx.x * 256 + tid; p < NPIX; p += KA_BLOCKS * 256) {
        const float v = var_at(x, p);
        g_var[p] = v;
        mn = fminf(mn, v);
        mx = fmaxf(mx, v);
    }
    __shared__ float smn[256], smx[256];
    smn[tid] = mn;
    smx[tid] = mx;
    __syncthreads();
    #pragma unroll
    for (int s = 128; s > 0; s >>= 1) {
        if (tid < s) {
            smn[tid] = fminf(smn[tid], smn[tid + s]);
            smx[tid] = fmaxf(smx[tid], smx[tid + s]);
        }
        __syncthreads();
    }
    if (tid == 0) {
        g_part[0][blockIdx.x] = smn[0];
        g_part[1][blockIdx.x] = smx[0];
    }
}

// kB: fold KA_BLOCKS partials into g_mm = {min, max}.
__global__ __launch_bounds__(256) void kB()
{
    const int tid = threadIdx.x;
    float mn = 3e38f, mx = -3e38f;
    for (int i = tid; i < KA_BLOCKS; i += 256) {
        mn = fminf(mn, g_part[0][i]);
        mx = fmaxf(mx, g_part[1][i]);
    }
    __shared__ float smn[256], smx[256];
    smn[tid] = mn;
    smx[tid] = mx;
    __syncthreads();
    #pragma unroll
    for (int s = 128; s > 0; s >>= 1) {
        if (tid < s) {
            smn[tid] = fminf(smn[tid], smn[tid + s]);
            smx[tid] = fmaxf(smx[tid], smx[tid + s]);
        }
        __syncthreads();
    }
    if (tid == 0) {
        g_mm[0] = smn[0];
        g_mm[1] = smx[0];
    }
}

// k3: streaming kernel (64 pixels / 1024 float4 per block), no LDS, no sync.
// lat computed inline (frozen chain). u4 is loaded ONLY when the quad's
// t-range [t0, t0+3] intersects the firing window [lat, lat+16) — otherwise
// the output quad is identically zero and the load is skipped (exec-mask
// predication; skipped lanes fetch no cache lines).
__global__ __launch_bounds__(256) void k3(const float* __restrict__ var,
                                          const float* __restrict__ x,
                                          const float4* __restrict__ u4,
                                          float4* __restrict__ out4)
{
    const int tid     = threadIdx.x;
    const int vecbase = blockIdx.x * 1024;
    const int pixbase = blockIdx.x * 64;
    const float t0 = (float)((tid & 15) * 4);
    const float t1 = t0 + 1.0f;
    const float t2 = t0 + 2.0f;
    const float t3 = t0 + 3.0f;
    const float mn = g_mm[0];
    const float mx = g_mm[1];

    #pragma unroll
    for (int j = 0; j < 4; ++j) {
        const int vec = vecbase + j * 256 + tid;
        const int pix = pixbase + j * 16 + (tid >> 4);
        const float n   = (var[pix] - mn) / (mx - mn);   // frozen lat chain
        const float d   = n + INV48_F;
        const float lat = 1.0f / d;
        const float hi  = lat + 16.0f;
        float4 o = make_float4(0.0f, 0.0f, 0.0f, 0.0f);
        // Quad intersects the firing window iff t3 >= lat && t0 < hi
        // (same frozen compare semantics; outside it every output is 0).
        if (t3 >= lat && t0 < hi) {
            const float  xv = x[pix];
            const float4 uu = u4[vec];
            o.x = (t0 >= lat && t0 < hi && uu.x < xv) ? 1.0f : 0.0f;
            o.y = (t1 >= lat && t1 < hi && uu.y < xv) ? 1.0f : 0.0f;
            o.z = (t2 >= lat && t2 < hi && uu.z < xv) ? 1.0f : 0.0f;
            o.w = (t3 >= lat && t3 < hi && uu.w < xv) ? 1.0f : 0.0f;
        }
        out4[vec] = o;
    }
}

extern "C" void kernel_launch(void* const* d_in, const int* in_sizes, int n_in,
                              void* d_out, int out_size, void* d_ws, size_t ws_size,
                              hipStream_t stream)
{
    const float* x = nullptr;
    const float* u = nullptr;
    for (int i = 0; i < n_in; ++i) {
        if (in_sizes[i] == NPIX)              x = (const float*)d_in[i];
        else if (in_sizes[i] == NPIX * T_WIN) u = (const float*)d_in[i];
    }
    if (!x) x = (const float*)d_in[0];
    if (!u) u = (const float*)d_in[1];
    float* out = (float*)d_out;

    kA<<<KA_BLOCKS, 256, 0, stream>>>(x);
    kB<<<1, 256, 0, stream>>>();

    float* varp = nullptr;
    hipGetSymbolAddress((void**)&varp, HIP_SYMBOL(g_var));
    k3<<<NPIX / 64, 256, 0, stream>>>(varp, x, (const float4*)u, (float4*)out);
}